// Round 1
// baseline (1288.227 us; speedup 1.0000x reference)
//
#include <hip/hip_runtime.h>

#define IN_FEAT 256
#define OUT_FEAT 128

// ---------------------------------------------------------------------------
// GEMM: femb[M,128] = feat[M,256] @ W[256,128], fp32 (no fp32 MFMA on CDNA4).
// Tile 64 rows x 128 cols per 256-thread block; thread = 4 rows x 8 cols.
// K chunked by 32 through LDS. sA stored transposed [k][row] so the inner
// A read is a single ds_read_b128 (<=2-way bank alias = free).
// ---------------------------------------------------------------------------
#define TM 64
#define KC 32

__global__ __launch_bounds__(256) void gemm_kernel(
    const float* __restrict__ A, const float* __restrict__ W,
    float* __restrict__ C, int M)
{
    __shared__ float sA[KC][TM + 4];      // pad 4 keeps 16B alignment of rows
    __shared__ float sW[KC][OUT_FEAT];

    const int t    = threadIdx.x;
    const int row0 = blockIdx.x * TM;
    const int r0   = 4 * (t & 15);        // rows r0..r0+3
    const int c0   = 8 * (t >> 4);        // cols c0..c0+7

    float acc[4][8];
    #pragma unroll
    for (int i = 0; i < 4; ++i)
        #pragma unroll
        for (int j = 0; j < 8; ++j) acc[i][j] = 0.f;

    // staging: thread loads A row (t>>2), k-cols 8*(t&3).. +7  (2 x float4)
    const int lr = t >> 2;
    const int lk = (t & 3) * 8;

    for (int kc = 0; kc < IN_FEAT; kc += KC) {
        int grow = row0 + lr;
        int grc  = grow < M ? grow : (M - 1);       // clamp, tail rows unused
        float4 a0 = *(const float4*)&A[(size_t)grc * IN_FEAT + kc + lk];
        float4 a1 = *(const float4*)&A[(size_t)grc * IN_FEAT + kc + lk + 4];
        sA[lk + 0][lr] = a0.x; sA[lk + 1][lr] = a0.y;
        sA[lk + 2][lr] = a0.z; sA[lk + 3][lr] = a0.w;
        sA[lk + 4][lr] = a1.x; sA[lk + 5][lr] = a1.y;
        sA[lk + 6][lr] = a1.z; sA[lk + 7][lr] = a1.w;
        {   // W tile 32x128: thread loads row t>>3, cols 16*(t&7)..+15
            const int wk = t >> 3;
            const int wc = (t & 7) * 16;
            const float4* src = (const float4*)&W[(size_t)(kc + wk) * OUT_FEAT + wc];
            float4* dst = (float4*)&sW[wk][wc];
            dst[0] = src[0]; dst[1] = src[1]; dst[2] = src[2]; dst[3] = src[3];
        }
        __syncthreads();

        #pragma unroll
        for (int k = 0; k < KC; ++k) {
            float4 a  = *(const float4*)&sA[k][r0];
            float4 w0 = *(const float4*)&sW[k][c0];
            float4 w1 = *(const float4*)&sW[k][c0 + 4];
            float av[4] = {a.x, a.y, a.z, a.w};
            float wv[8] = {w0.x, w0.y, w0.z, w0.w, w1.x, w1.y, w1.z, w1.w};
            #pragma unroll
            for (int i = 0; i < 4; ++i)
                #pragma unroll
                for (int j = 0; j < 8; ++j)
                    acc[i][j] = fmaf(av[i], wv[j], acc[i][j]);
        }
        __syncthreads();
    }

    #pragma unroll
    for (int i = 0; i < 4; ++i) {
        int grow = row0 + r0 + i;
        if (grow < M) {
            float4 o0 = {acc[i][0], acc[i][1], acc[i][2], acc[i][3]};
            float4 o1 = {acc[i][4], acc[i][5], acc[i][6], acc[i][7]};
            *(float4*)&C[(size_t)grow * OUT_FEAT + c0]     = o0;
            *(float4*)&C[(size_t)grow * OUT_FEAT + c0 + 4] = o1;
        }
    }
}

// ---------------------------------------------------------------------------
// zero-fill x (d_out is poisoned 0xAA; zero-degree rows must be 0)
// ---------------------------------------------------------------------------
__global__ void zero_kernel(float4* __restrict__ p, int n4)
{
    int i      = blockIdx.x * blockDim.x + threadIdx.x;
    int stride = gridDim.x * blockDim.x;
    for (; i < n4; i += stride) p[i] = float4{0.f, 0.f, 0.f, 0.f};
}

// ---------------------------------------------------------------------------
// SpMM over sorted COO: x[row[e]] += val[e] * femb[col[e]].
// One wave per block; lane owns 2 feature cols (float2 -> 512B coalesced
// gather per wave). Block walks a contiguous edge chunk; since rows are
// sorted, accumulate in registers and flush (atomicAdd, device scope) only
// when the row changes. Atomics handle rows straddling chunk boundaries.
// ---------------------------------------------------------------------------
__global__ __launch_bounds__(64) void spmm_kernel(
    const int*   __restrict__ erow, const int* __restrict__ ecol,
    const float* __restrict__ eval, const float* __restrict__ femb,
    float* __restrict__ x, int E, int epb)
{
    int e0 = blockIdx.x * epb;
    int e1 = min(E, e0 + epb);
    if (e0 >= e1) return;

    const int j = threadIdx.x * 2;
    float2 acc = {0.f, 0.f};
    int cur = erow[e0];

    for (int e = e0; e < e1; ++e) {
        int r = erow[e];                 // wave-uniform
        if (r != cur) {                  // uniform branch: segment flush
            atomicAdd(&x[(size_t)cur * OUT_FEAT + j],     acc.x);
            atomicAdd(&x[(size_t)cur * OUT_FEAT + j + 1], acc.y);
            acc.x = 0.f; acc.y = 0.f;
            cur = r;
        }
        float  v = eval[e];              // wave-uniform
        float2 f = *(const float2*)&femb[(size_t)ecol[e] * OUT_FEAT + j];
        acc.x = fmaf(v, f.x, acc.x);
        acc.y = fmaf(v, f.y, acc.y);
    }
    atomicAdd(&x[(size_t)cur * OUT_FEAT + j],     acc.x);
    atomicAdd(&x[(size_t)cur * OUT_FEAT + j + 1], acc.y);
}

// ---------------------------------------------------------------------------
extern "C" void kernel_launch(void* const* d_in, const int* in_sizes, int n_in,
                              void* d_out, int out_size, void* d_ws, size_t ws_size,
                              hipStream_t stream)
{
    const float* feat = (const float*)d_in[0];
    const int*   erow = (const int*)  d_in[1];
    const int*   ecol = (const int*)  d_in[2];
    const float* eval = (const float*)d_in[3];
    const float* W    = (const float*)d_in[4];

    const int M = in_sizes[0] / IN_FEAT;   // 100000
    const int E = in_sizes[1];             // 3200000

    float* femb = (float*)d_out;                        // output 0: [M,128]
    float* x    = (float*)d_out + (size_t)M * OUT_FEAT; // output 1: [M,128]

    // 1. femb = feat @ W
    gemm_kernel<<<(M + TM - 1) / TM, 256, 0, stream>>>(feat, W, femb, M);

    // 2. x = 0
    int n4 = (M * OUT_FEAT) / 4;
    zero_kernel<<<2048, 256, 0, stream>>>((float4*)x, n4);

    // 3. x[row] += val * femb[col]
    const int EPB  = 256;
    int nblk = (E + EPB - 1) / EPB;
    spmm_kernel<<<nblk, 64, 0, stream>>>(erow, ecol, eval, femb, x, E, EPB);
}

// Round 2
// 524.086 us; speedup vs baseline: 2.4580x; 2.4580x over previous
//
#include <hip/hip_runtime.h>

#define IN_FEAT 256
#define OUT_FEAT 128

// ---------------------------------------------------------------------------
// GEMM: femb[M,128] = feat[M,256] @ W[256,128], fp32 (no fp32 MFMA on CDNA4).
// Tile 64 rows x 128 cols per 256-thread block; thread = 4 rows x 8 cols.
// ---------------------------------------------------------------------------
#define TM 64
#define KC 32

__global__ __launch_bounds__(256) void gemm_kernel(
    const float* __restrict__ A, const float* __restrict__ W,
    float* __restrict__ C, int M)
{
    __shared__ float sA[KC][TM + 4];
    __shared__ float sW[KC][OUT_FEAT];

    const int t    = threadIdx.x;
    const int row0 = blockIdx.x * TM;
    const int r0   = 4 * (t & 15);
    const int c0   = 8 * (t >> 4);

    float acc[4][8];
    #pragma unroll
    for (int i = 0; i < 4; ++i)
        #pragma unroll
        for (int j = 0; j < 8; ++j) acc[i][j] = 0.f;

    const int lr = t >> 2;
    const int lk = (t & 3) * 8;

    for (int kc = 0; kc < IN_FEAT; kc += KC) {
        int grow = row0 + lr;
        int grc  = grow < M ? grow : (M - 1);
        float4 a0 = *(const float4*)&A[(size_t)grc * IN_FEAT + kc + lk];
        float4 a1 = *(const float4*)&A[(size_t)grc * IN_FEAT + kc + lk + 4];
        sA[lk + 0][lr] = a0.x; sA[lk + 1][lr] = a0.y;
        sA[lk + 2][lr] = a0.z; sA[lk + 3][lr] = a0.w;
        sA[lk + 4][lr] = a1.x; sA[lk + 5][lr] = a1.y;
        sA[lk + 6][lr] = a1.z; sA[lk + 7][lr] = a1.w;
        {
            const int wk = t >> 3;
            const int wc = (t & 7) * 16;
            const float4* src = (const float4*)&W[(size_t)(kc + wk) * OUT_FEAT + wc];
            float4* dst = (float4*)&sW[wk][wc];
            dst[0] = src[0]; dst[1] = src[1]; dst[2] = src[2]; dst[3] = src[3];
        }
        __syncthreads();

        #pragma unroll
        for (int k = 0; k < KC; ++k) {
            float4 a  = *(const float4*)&sA[k][r0];
            float4 w0 = *(const float4*)&sW[k][c0];
            float4 w1 = *(const float4*)&sW[k][c0 + 4];
            float av[4] = {a.x, a.y, a.z, a.w};
            float wv[8] = {w0.x, w0.y, w0.z, w0.w, w1.x, w1.y, w1.z, w1.w};
            #pragma unroll
            for (int i = 0; i < 4; ++i)
                #pragma unroll
                for (int j = 0; j < 8; ++j)
                    acc[i][j] = fmaf(av[i], wv[j], acc[i][j]);
        }
        __syncthreads();
    }

    #pragma unroll
    for (int i = 0; i < 4; ++i) {
        int grow = row0 + r0 + i;
        if (grow < M) {
            float4 o0 = {acc[i][0], acc[i][1], acc[i][2], acc[i][3]};
            float4 o1 = {acc[i][4], acc[i][5], acc[i][6], acc[i][7]};
            *(float4*)&C[(size_t)grow * OUT_FEAT + c0]     = o0;
            *(float4*)&C[(size_t)grow * OUT_FEAT + c0 + 4] = o1;
        }
    }
}

// ---------------------------------------------------------------------------
// zero-fill x
// ---------------------------------------------------------------------------
__global__ void zero_kernel(float4* __restrict__ p, int n4)
{
    int i      = blockIdx.x * blockDim.x + threadIdx.x;
    int stride = gridDim.x * blockDim.x;
    for (; i < n4; i += stride) p[i] = float4{0.f, 0.f, 0.f, 0.f};
}

// ---------------------------------------------------------------------------
// SpMM over sorted COO, latency-optimized:
//  - edge row/col/val staged cooperatively in LDS (coalesced, then broadcast)
//  - 4 waves/block, each wave owns a contiguous 128-edge sub-chunk
//  - gathers issued 8-deep (statically indexed f[8]) before consumption -> MLP x8
//  - register accumulation per sorted segment, atomicAdd flush on row change
// ---------------------------------------------------------------------------
#define EPB 512          // edges per block
#define EPW 128          // edges per wave
#define PF  8            // prefetch depth

__global__ __launch_bounds__(256) void spmm_kernel(
    const int*   __restrict__ erow, const int* __restrict__ ecol,
    const float* __restrict__ eval, const float* __restrict__ femb,
    float* __restrict__ x, int E)
{
    __shared__ int   s_row[EPB];
    __shared__ int   s_col[EPB];
    __shared__ float s_val[EPB];

    const int blockBase = blockIdx.x * EPB;

    // cooperative coalesced staging: 512 edges, 256 threads, 2 each
    #pragma unroll
    for (int i = 0; i < 2; ++i) {
        int li = threadIdx.x + i * 256;
        int e  = blockBase + li;
        if (e < E) {
            s_row[li] = erow[e];
            s_col[li] = ecol[e];
            s_val[li] = eval[e];
        }
    }
    __syncthreads();

    const int wave = threadIdx.x >> 6;
    const int lane = threadIdx.x & 63;
    const int j    = lane * 2;           // this lane's 2 feature cols

    const int w0 = wave * EPW;           // LDS-local start of this wave's chunk
    const int g0 = blockBase + w0;
    if (g0 >= E) return;
    const int n = min(EPW, E - g0);

    float2 acc = {0.f, 0.f};
    int cur = s_row[w0];

    for (int base = 0; base < n; base += PF) {
        const int m = min(PF, n - base);

        // issue all gathers for this group first (independent, 8 outstanding)
        float2 f[PF];
        #pragma unroll
        for (int i = 0; i < PF; ++i) {
            if (i < m) {
                int c = s_col[w0 + base + i];            // LDS broadcast
                f[i] = *(const float2*)&femb[(size_t)c * OUT_FEAT + j];
            }
        }

        // consume
        #pragma unroll
        for (int i = 0; i < PF; ++i) {
            if (i < m) {
                int r = s_row[w0 + base + i];            // wave-uniform
                if (r != cur) {                          // uniform flush
                    atomicAdd(&x[(size_t)cur * OUT_FEAT + j],     acc.x);
                    atomicAdd(&x[(size_t)cur * OUT_FEAT + j + 1], acc.y);
                    acc.x = 0.f; acc.y = 0.f;
                    cur = r;
                }
                float v = s_val[w0 + base + i];
                acc.x = fmaf(v, f[i].x, acc.x);
                acc.y = fmaf(v, f[i].y, acc.y);
            }
        }
    }
    atomicAdd(&x[(size_t)cur * OUT_FEAT + j],     acc.x);
    atomicAdd(&x[(size_t)cur * OUT_FEAT + j + 1], acc.y);
}

// ---------------------------------------------------------------------------
extern "C" void kernel_launch(void* const* d_in, const int* in_sizes, int n_in,
                              void* d_out, int out_size, void* d_ws, size_t ws_size,
                              hipStream_t stream)
{
    const float* feat = (const float*)d_in[0];
    const int*   erow = (const int*)  d_in[1];
    const int*   ecol = (const int*)  d_in[2];
    const float* eval = (const float*)d_in[3];
    const float* W    = (const float*)d_in[4];

    const int M = in_sizes[0] / IN_FEAT;   // 100000
    const int E = in_sizes[1];             // 3200000

    float* femb = (float*)d_out;                        // output 0: [M,128]
    float* x    = (float*)d_out + (size_t)M * OUT_FEAT; // output 1: [M,128]

    // 1. femb = feat @ W
    gemm_kernel<<<(M + TM - 1) / TM, 256, 0, stream>>>(feat, W, femb, M);

    // 2. x = 0
    int n4 = (M * OUT_FEAT) / 4;
    zero_kernel<<<2048, 256, 0, stream>>>((float4*)x, n4);

    // 3. x[row] += val * femb[col]
    int nblk = (E + EPB - 1) / EPB;
    spmm_kernel<<<nblk, 256, 0, stream>>>(erow, ecol, eval, femb, x, E);
}

// Round 3
// 391.227 us; speedup vs baseline: 3.2928x; 1.3396x over previous
//
#include <hip/hip_runtime.h>
#include <hip/hip_fp16.h>

#define IN_FEAT 256
#define OUT_FEAT 128

// ---------------------------------------------------------------------------
// GEMM: femb[M,128] = feat[M,256] @ W[256,128], fp32 vector-ALU (no fp32 MFMA).
// 128x128 block tile, 256 threads, 8x8 per thread (2 flop / LDS-byte).
// sA transposed [k][row]: per-wave A reads are 16-lane broadcasts (free).
// sW [k][col]: 16 lanes x float4 cover 64 consecutive floats = 2-way (free).
// Also emits an fp16 copy of femb into d_ws for the spmm gather.
// ---------------------------------------------------------------------------
#define GTM 128
#define KC  32

__global__ __launch_bounds__(256, 2) void gemm_kernel(
    const float* __restrict__ A, const float* __restrict__ W,
    float* __restrict__ C, __half* __restrict__ Ch, int M, int writeHalf)
{
    __shared__ float sA[KC][GTM];        // [k][row]
    __shared__ float sW[KC][OUT_FEAT];   // [k][col]

    const int t    = threadIdx.x;
    const int row0 = blockIdx.x * GTM;
    const int tr   = t >> 4;             // 0..15
    const int tc   = t & 15;             // 0..15

    float acc[8][8];
    #pragma unroll
    for (int i = 0; i < 8; ++i)
        #pragma unroll
        for (int j = 0; j < 8; ++j) acc[i][j] = 0.f;

    // A staging: thread loads row t>>1, 16 k-values at offset (t&1)*16
    const int ar = t >> 1;
    const int ak = (t & 1) * 16;

    for (int kc = 0; kc < IN_FEAT; kc += KC) {
        {
            int grow = row0 + ar;
            const float* Ap = &A[(size_t)(grow < M ? grow : (M - 1)) * IN_FEAT + kc + ak];
            float4 a0 = *(const float4*)(Ap + 0);
            float4 a1 = *(const float4*)(Ap + 4);
            float4 a2 = *(const float4*)(Ap + 8);
            float4 a3 = *(const float4*)(Ap + 12);
            sA[ak + 0][ar] = a0.x; sA[ak + 1][ar] = a0.y; sA[ak + 2][ar] = a0.z; sA[ak + 3][ar] = a0.w;
            sA[ak + 4][ar] = a1.x; sA[ak + 5][ar] = a1.y; sA[ak + 6][ar] = a1.z; sA[ak + 7][ar] = a1.w;
            sA[ak + 8][ar] = a2.x; sA[ak + 9][ar] = a2.y; sA[ak +10][ar] = a2.z; sA[ak +11][ar] = a2.w;
            sA[ak +12][ar] = a3.x; sA[ak +13][ar] = a3.y; sA[ak +14][ar] = a3.z; sA[ak +15][ar] = a3.w;
        }
        {   // W chunk is contiguous [kc..kc+31][0..127] -> plain linear copy
            const float4* Wp  = (const float4*)&W[(size_t)kc * OUT_FEAT];
            float4*       sWp = (float4*)&sW[0][0];
            #pragma unroll
            for (int i = 0; i < 4; ++i) sWp[t + 256 * i] = Wp[t + 256 * i];
        }
        __syncthreads();

        #pragma unroll 8
        for (int k = 0; k < KC; ++k) {
            float4 a0v = *(const float4*)&sA[k][4 * tr];
            float4 a1v = *(const float4*)&sA[k][64 + 4 * tr];
            float4 w0v = *(const float4*)&sW[k][4 * tc];
            float4 w1v = *(const float4*)&sW[k][64 + 4 * tc];
            float av[8] = {a0v.x, a0v.y, a0v.z, a0v.w, a1v.x, a1v.y, a1v.z, a1v.w};
            float wv[8] = {w0v.x, w0v.y, w0v.z, w0v.w, w1v.x, w1v.y, w1v.z, w1v.w};
            #pragma unroll
            for (int ri = 0; ri < 8; ++ri)
                #pragma unroll
                for (int ci = 0; ci < 8; ++ci)
                    acc[ri][ci] = fmaf(av[ri], wv[ci], acc[ri][ci]);
        }
        __syncthreads();
    }

    #pragma unroll
    for (int ri = 0; ri < 8; ++ri) {
        int r = row0 + (ri < 4 ? 4 * tr + ri : 64 + 4 * tr + (ri - 4));
        if (r < M) {
            float4 o0 = {acc[ri][0], acc[ri][1], acc[ri][2], acc[ri][3]};
            float4 o1 = {acc[ri][4], acc[ri][5], acc[ri][6], acc[ri][7]};
            *(float4*)&C[(size_t)r * OUT_FEAT + 4 * tc]      = o0;
            *(float4*)&C[(size_t)r * OUT_FEAT + 64 + 4 * tc] = o1;
            if (writeHalf) {
                __half2 h01 = __floats2half2_rn(o0.x, o0.y);
                __half2 h23 = __floats2half2_rn(o0.z, o0.w);
                __half2 h45 = __floats2half2_rn(o1.x, o1.y);
                __half2 h67 = __floats2half2_rn(o1.z, o1.w);
                *(__half2*)&Ch[(size_t)r * OUT_FEAT + 4 * tc]          = h01;
                *(__half2*)&Ch[(size_t)r * OUT_FEAT + 4 * tc + 2]      = h23;
                *(__half2*)&Ch[(size_t)r * OUT_FEAT + 64 + 4 * tc]     = h45;
                *(__half2*)&Ch[(size_t)r * OUT_FEAT + 64 + 4 * tc + 2] = h67;
            }
        }
    }
}

// ---------------------------------------------------------------------------
// zero-fill x
// ---------------------------------------------------------------------------
__global__ void zero_kernel(float4* __restrict__ p, int n4)
{
    int i      = blockIdx.x * blockDim.x + threadIdx.x;
    int stride = gridDim.x * blockDim.x;
    for (; i < n4; i += stride) p[i] = float4{0.f, 0.f, 0.f, 0.f};
}

// ---------------------------------------------------------------------------
// SpMM over sorted COO. Edge data staged in LDS (nontemporal global reads);
// 4 waves/block each owning 128 contiguous edges; gathers 16-deep from the
// fp16 femb copy (half traffic); register segment accumulation + atomic flush.
// ---------------------------------------------------------------------------
#define EPB 512
#define EPW 128
#define PF  16

template<int USE_H>
__global__ __launch_bounds__(256) void spmm_kernel(
    const int*   __restrict__ erow, const int* __restrict__ ecol,
    const float* __restrict__ eval, const float* __restrict__ femb,
    const __half* __restrict__ fembh, float* __restrict__ x, int E)
{
    __shared__ int   s_row[EPB];
    __shared__ int   s_col[EPB];
    __shared__ float s_val[EPB];

    const int blockBase = blockIdx.x * EPB;

    #pragma unroll
    for (int i = 0; i < 2; ++i) {
        int li = threadIdx.x + i * 256;
        int e  = blockBase + li;
        if (e < E) {
            s_row[li] = __builtin_nontemporal_load(&erow[e]);
            s_col[li] = __builtin_nontemporal_load(&ecol[e]);
            s_val[li] = __builtin_nontemporal_load(&eval[e]);
        }
    }
    __syncthreads();

    const int wave = threadIdx.x >> 6;
    const int lane = threadIdx.x & 63;
    const int j    = lane * 2;

    const int w0 = wave * EPW;
    const int g0 = blockBase + w0;
    if (g0 >= E) return;
    const int n = min(EPW, E - g0);

    float2 acc = {0.f, 0.f};
    int cur = s_row[w0];

    if (n == EPW) {
        #pragma unroll 1
        for (int base = 0; base < EPW; base += PF) {
            __half2 h[PF];
            float2  f[PF];
            if constexpr (USE_H) {
                #pragma unroll
                for (int i = 0; i < PF; ++i) {
                    int c = s_col[w0 + base + i];
                    h[i] = *(const __half2*)&fembh[(size_t)c * OUT_FEAT + j];
                }
            } else {
                #pragma unroll
                for (int i = 0; i < PF; ++i) {
                    int c = s_col[w0 + base + i];
                    f[i] = *(const float2*)&femb[(size_t)c * OUT_FEAT + j];
                }
            }
            #pragma unroll
            for (int i = 0; i < PF; ++i) {
                int r = s_row[w0 + base + i];
                if (r != cur) {
                    atomicAdd(&x[(size_t)cur * OUT_FEAT + j],     acc.x);
                    atomicAdd(&x[(size_t)cur * OUT_FEAT + j + 1], acc.y);
                    acc.x = 0.f; acc.y = 0.f;
                    cur = r;
                }
                float v = s_val[w0 + base + i];
                float2 fv;
                if constexpr (USE_H) fv = __half22float2(h[i]); else fv = f[i];
                acc.x = fmaf(v, fv.x, acc.x);
                acc.y = fmaf(v, fv.y, acc.y);
            }
        }
    } else {
        for (int idx = 0; idx < n; ++idx) {
            int r = s_row[w0 + idx];
            if (r != cur) {
                atomicAdd(&x[(size_t)cur * OUT_FEAT + j],     acc.x);
                atomicAdd(&x[(size_t)cur * OUT_FEAT + j + 1], acc.y);
                acc.x = 0.f; acc.y = 0.f;
                cur = r;
            }
            int c = s_col[w0 + idx];
            float v = s_val[w0 + idx];
            float2 fv;
            if constexpr (USE_H) fv = __half22float2(*(const __half2*)&fembh[(size_t)c * OUT_FEAT + j]);
            else                 fv = *(const float2*)&femb[(size_t)c * OUT_FEAT + j];
            acc.x = fmaf(v, fv.x, acc.x);
            acc.y = fmaf(v, fv.y, acc.y);
        }
    }
    atomicAdd(&x[(size_t)cur * OUT_FEAT + j],     acc.x);
    atomicAdd(&x[(size_t)cur * OUT_FEAT + j + 1], acc.y);
}

// ---------------------------------------------------------------------------
extern "C" void kernel_launch(void* const* d_in, const int* in_sizes, int n_in,
                              void* d_out, int out_size, void* d_ws, size_t ws_size,
                              hipStream_t stream)
{
    const float* feat = (const float*)d_in[0];
    const int*   erow = (const int*)  d_in[1];
    const int*   ecol = (const int*)  d_in[2];
    const float* eval = (const float*)d_in[3];
    const float* W    = (const float*)d_in[4];

    const int M = in_sizes[0] / IN_FEAT;   // 100000
    const int E = in_sizes[1];             // 3200000

    float*  femb  = (float*)d_out;
    float*  x     = femb + (size_t)M * OUT_FEAT;
    __half* fembh = (__half*)d_ws;

    const size_t needH = (size_t)M * OUT_FEAT * sizeof(__half);
    const int useH = (ws_size >= needH) ? 1 : 0;

    gemm_kernel<<<(M + GTM - 1) / GTM, 256, 0, stream>>>(feat, W, femb, fembh, M, useH);

    zero_kernel<<<2048, 256, 0, stream>>>((float4*)x, (M * OUT_FEAT) / 4);

    int nblk = (E + EPB - 1) / EPB;
    if (useH) spmm_kernel<1><<<nblk, 256, 0, stream>>>(erow, ecol, eval, femb, fembh, x, E);
    else      spmm_kernel<0><<<nblk, 256, 0, stream>>>(erow, ecol, eval, femb, fembh, x, E);
}

// Round 5
// 361.969 us; speedup vs baseline: 3.5589x; 1.0808x over previous
//
#include <hip/hip_runtime.h>
#include <hip/hip_fp16.h>

#define IN_FEAT 256
#define OUT_FEAT 128

typedef _Float16 half8 __attribute__((ext_vector_type(8)));
typedef float    f32x4 __attribute__((ext_vector_type(4)));

// ---------------------------------------------------------------------------
// GEMM via f16 MFMA: femb[M,128] = feat[M,256] @ W[256,128], fp32 accum.
// One 128-row x 128-col tile per 512-thread block; whole K=256 staged in LDS
// once (A: 64KB f16, W^T: 64KB f16, both XOR-swizzled -> even 8-slot spread
// for all ds_read_b128 / staging writes). 8 waves x 16 rows; 64 MFMA/wave.
// HBM-bound by design (~28us floor). Also emits fp16 femb copy for spmm.
// ---------------------------------------------------------------------------
#define GBM 128
#define GT  512

__global__ __launch_bounds__(GT, 1) void gemm_mfma_kernel(
    const float* __restrict__ A, const float* __restrict__ W,
    float* __restrict__ C, __half* __restrict__ Ch, int M, int writeHalf)
{
    __shared__ _Float16 sA[GBM * IN_FEAT];      // [row][k], swizzled
    __shared__ _Float16 sW[OUT_FEAT * IN_FEAT]; // [col][k], swizzled

    const int t    = threadIdx.x;
    const int row0 = blockIdx.x * GBM;

    // ---- stage A: fp32 -> f16, row-major, XOR-swizzled ----
    {
        const int row = t >> 2;                 // 0..127
        const int kq  = t & 3;
        int grow = row0 + row; if (grow >= M) grow = M - 1;
        const float* Ap = &A[(size_t)grow * IN_FEAT];
        #pragma unroll
        for (int i = 0; i < 8; ++i) {
            int k = kq * 8 + i * 32;
            float4 a0 = *(const float4*)(Ap + k);
            float4 a1 = *(const float4*)(Ap + k + 4);
            half8 h;
            h[0]=(_Float16)a0.x; h[1]=(_Float16)a0.y; h[2]=(_Float16)a0.z; h[3]=(_Float16)a0.w;
            h[4]=(_Float16)a1.x; h[5]=(_Float16)a1.y; h[6]=(_Float16)a1.z; h[7]=(_Float16)a1.w;
            int byte = row * 512 + k * 2;
            byte ^= (row & 7) << 4;
            *(half8*)((char*)sA + byte) = h;
        }
    }
    // ---- stage W^T: fp32 -> f16, transpose, XOR-swizzled ----
    {
        const int col = t & 127;
        const int kq  = t >> 7;                 // 0..3
        #pragma unroll
        for (int i = 0; i < 16; ++i) {
            int k = kq * 64 + i * 4;
            _Float16 h[4];
            h[0] = (_Float16)W[(size_t)(k+0) * OUT_FEAT + col];
            h[1] = (_Float16)W[(size_t)(k+1) * OUT_FEAT + col];
            h[2] = (_Float16)W[(size_t)(k+2) * OUT_FEAT + col];
            h[3] = (_Float16)W[(size_t)(k+3) * OUT_FEAT + col];
            int byte = col * 512 + k * 2;       // k%4==0 -> byte%8==0
            byte ^= (col & 7) << 4;
            *(unsigned long long*)((char*)sW + byte) = *(const unsigned long long*)h;
        }
    }
    __syncthreads();

    // ---- compute: wave owns 16 rows x 128 cols ----
    const int wid  = t >> 6;
    const int lane = t & 63;
    const int rowBase = wid * 16;
    const int fr = lane & 15;                   // A row / B col within tile
    const int fk = lane >> 4;                   // k subgroup

    f32x4 acc[8];
    #pragma unroll
    for (int nt = 0; nt < 8; ++nt) acc[nt] = (f32x4){0.f, 0.f, 0.f, 0.f};

    #pragma unroll
    for (int ks = 0; ks < 8; ++ks) {
        const int arow  = rowBase + fr;
        int abyte = arow * 512 + ks * 64 + fk * 16;
        abyte ^= (arow & 7) << 4;
        half8 af = *(const half8*)((const char*)sA + abyte);
        #pragma unroll
        for (int nt = 0; nt < 8; ++nt) {
            const int col = nt * 16 + fr;
            int bbyte = col * 512 + ks * 64 + fk * 16;
            bbyte ^= (col & 7) << 4;
            half8 bf = *(const half8*)((const char*)sW + bbyte);
            acc[nt] = __builtin_amdgcn_mfma_f32_16x16x32_f16(af, bf, acc[nt], 0, 0, 0);
        }
    }

    // ---- store: C/D layout col=lane&15, row=(lane>>4)*4+reg (m89-verified) --
    const int drow = fk * 4;
    #pragma unroll
    for (int nt = 0; nt < 8; ++nt) {
        #pragma unroll
        for (int r = 0; r < 4; ++r) {
            int grow = row0 + rowBase + drow + r;
            if (grow < M) {
                int col = nt * 16 + fr;
                C[(size_t)grow * OUT_FEAT + col] = acc[nt][r];
                if (writeHalf)
                    *(_Float16*)&Ch[(size_t)grow * OUT_FEAT + col] = (_Float16)acc[nt][r];
            }
        }
    }
}

// ---------------------------------------------------------------------------
// zero-fill x
// ---------------------------------------------------------------------------
__global__ void zero_kernel(float4* __restrict__ p, int n4)
{
    int i      = blockIdx.x * blockDim.x + threadIdx.x;
    int stride = gridDim.x * blockDim.x;
    for (; i < n4; i += stride) p[i] = float4{0.f, 0.f, 0.f, 0.f};
}

// ---------------------------------------------------------------------------
// SpMM over sorted COO (unchanged from R3: 138us, FETCH halved via fp16 femb).
// ---------------------------------------------------------------------------
#define EPB 512
#define EPW 128
#define PF  16

template<int USE_H>
__global__ __launch_bounds__(256) void spmm_kernel(
    const int*   __restrict__ erow, const int* __restrict__ ecol,
    const float* __restrict__ eval, const float* __restrict__ femb,
    const __half* __restrict__ fembh, float* __restrict__ x, int E)
{
    __shared__ int   s_row[EPB];
    __shared__ int   s_col[EPB];
    __shared__ float s_val[EPB];

    const int blockBase = blockIdx.x * EPB;

    #pragma unroll
    for (int i = 0; i < 2; ++i) {
        int li = threadIdx.x + i * 256;
        int e  = blockBase + li;
        if (e < E) {
            s_row[li] = __builtin_nontemporal_load(&erow[e]);
            s_col[li] = __builtin_nontemporal_load(&ecol[e]);
            s_val[li] = __builtin_nontemporal_load(&eval[e]);
        }
    }
    __syncthreads();

    const int wave = threadIdx.x >> 6;
    const int lane = threadIdx.x & 63;
    const int j    = lane * 2;

    const int w0 = wave * EPW;
    const int g0 = blockBase + w0;
    if (g0 >= E) return;
    const int n = min(EPW, E - g0);

    float2 acc = {0.f, 0.f};
    int cur = s_row[w0];

    if (n == EPW) {
        #pragma unroll 1
        for (int base = 0; base < EPW; base += PF) {
            __half2 h[PF];
            float2  f[PF];
            if constexpr (USE_H) {
                #pragma unroll
                for (int i = 0; i < PF; ++i) {
                    int c = s_col[w0 + base + i];
                    h[i] = *(const __half2*)&fembh[(size_t)c * OUT_FEAT + j];
                }
            } else {
                #pragma unroll
                for (int i = 0; i < PF; ++i) {
                    int c = s_col[w0 + base + i];
                    f[i] = *(const float2*)&femb[(size_t)c * OUT_FEAT + j];
                }
            }
            #pragma unroll
            for (int i = 0; i < PF; ++i) {
                int r = s_row[w0 + base + i];
                if (r != cur) {
                    atomicAdd(&x[(size_t)cur * OUT_FEAT + j],     acc.x);
                    atomicAdd(&x[(size_t)cur * OUT_FEAT + j + 1], acc.y);
                    acc.x = 0.f; acc.y = 0.f;
                    cur = r;
                }
                float v = s_val[w0 + base + i];
                float2 fv;
                if constexpr (USE_H) fv = __half22float2(h[i]); else fv = f[i];
                acc.x = fmaf(v, fv.x, acc.x);
                acc.y = fmaf(v, fv.y, acc.y);
            }
        }
    } else {
        for (int idx = 0; idx < n; ++idx) {
            int r = s_row[w0 + idx];
            if (r != cur) {
                atomicAdd(&x[(size_t)cur * OUT_FEAT + j],     acc.x);
                atomicAdd(&x[(size_t)cur * OUT_FEAT + j + 1], acc.y);
                acc.x = 0.f; acc.y = 0.f;
                cur = r;
            }
            int c = s_col[w0 + idx];
            float v = s_val[w0 + idx];
            float2 fv;
            if constexpr (USE_H) fv = __half22float2(*(const __half2*)&fembh[(size_t)c * OUT_FEAT + j]);
            else                 fv = *(const float2*)&femb[(size_t)c * OUT_FEAT + j];
            acc.x = fmaf(v, fv.x, acc.x);
            acc.y = fmaf(v, fv.y, acc.y);
        }
    }
    atomicAdd(&x[(size_t)cur * OUT_FEAT + j],     acc.x);
    atomicAdd(&x[(size_t)cur * OUT_FEAT + j + 1], acc.y);
}

// ---------------------------------------------------------------------------
extern "C" void kernel_launch(void* const* d_in, const int* in_sizes, int n_in,
                              void* d_out, int out_size, void* d_ws, size_t ws_size,
                              hipStream_t stream)
{
    const float* feat = (const float*)d_in[0];
    const int*   erow = (const int*)  d_in[1];
    const int*   ecol = (const int*)  d_in[2];
    const float* eval = (const float*)d_in[3];
    const float* W    = (const float*)d_in[4];

    const int M = in_sizes[0] / IN_FEAT;   // 100000
    const int E = in_sizes[1];             // 3200000

    float*  femb  = (float*)d_out;
    float*  x     = femb + (size_t)M * OUT_FEAT;
    __half* fembh = (__half*)d_ws;

    const size_t needH = (size_t)M * OUT_FEAT * sizeof(__half);
    const int useH = (ws_size >= needH) ? 1 : 0;

    gemm_mfma_kernel<<<(M + GBM - 1) / GBM, GT, 0, stream>>>(feat, W, femb, fembh, M, useH);

    zero_kernel<<<2048, 256, 0, stream>>>((float4*)x, (M * OUT_FEAT) / 4);

    int nblk = (E + EPB - 1) / EPB;
    if (useH) spmm_kernel<1><<<nblk, 256, 0, stream>>>(erow, ecol, eval, femb, fembh, x, E);
    else      spmm_kernel<0><<<nblk, 256, 0, stream>>>(erow, ecol, eval, femb, fembh, x, E);
}

// Round 6
// 359.504 us; speedup vs baseline: 3.5833x; 1.0069x over previous
//
#include <hip/hip_runtime.h>
#include <hip/hip_fp16.h>

#define IN_FEAT 256
#define OUT_FEAT 128

typedef _Float16 half8 __attribute__((ext_vector_type(8)));
typedef _Float16 half4 __attribute__((ext_vector_type(4)));
typedef float    f32x4 __attribute__((ext_vector_type(4)));

#define WT_BYTES (OUT_FEAT * IN_FEAT * 2)   // 64 KB fp16 W^T image

// ---------------------------------------------------------------------------
// wprep: W[256,128] fp32 -> W^T[col][k] fp16, XOR-swizzled exactly as the
// gemm LDS image (byte = col*512 + k*2, ^ (col&7)<<4). Runs once per launch;
// 64 KB output stays L2-hot for all gemm blocks.
// ---------------------------------------------------------------------------
__global__ __launch_bounds__(256) void wprep_kernel(
    const float* __restrict__ W, char* __restrict__ wt)
{
    int t   = blockIdx.x * blockDim.x + threadIdx.x;   // 0..16383
    int col = t & 127;
    int k   = (t >> 7) * 2;                            // even k
    _Float16 h0 = (_Float16)W[(size_t)k       * OUT_FEAT + col];
    _Float16 h1 = (_Float16)W[(size_t)(k + 1) * OUT_FEAT + col];
    int byte = col * 512 + k * 2;
    byte ^= (col & 7) << 4;                            // 4B-aligned preserved
    unsigned short u0, u1;
    __builtin_memcpy(&u0, &h0, 2);
    __builtin_memcpy(&u1, &h1, 2);
    *(unsigned int*)(wt + byte) = (unsigned int)u0 | ((unsigned int)u1 << 16);
}

// ---------------------------------------------------------------------------
// GEMM via f16 MFMA: femb[M,128] = feat[M,256] @ W[256,128], fp32 accum.
// 128-row tile / 512-thread block; whole K=256 in LDS (A 64KB + W^T 64KB,
// both XOR-swizzled). W^T staged by linear 64KB copy from wprep's image.
// MFMA operands SWAPPED -> lane owns 4 consecutive cols of one row ->
// float4/half4 epilogue stores. Also emits fp16 femb copy for spmm.
// ---------------------------------------------------------------------------
#define GBM 128
#define GT  512

__global__ __launch_bounds__(GT, 1) void gemm_mfma_kernel(
    const float* __restrict__ A, const char* __restrict__ wt,
    float* __restrict__ C, __half* __restrict__ Ch, int M, int writeHalf)
{
    __shared__ _Float16 sA[GBM * IN_FEAT];      // [row][k], swizzled
    __shared__ _Float16 sW[OUT_FEAT * IN_FEAT]; // [col][k], swizzled

    const int t    = threadIdx.x;
    const int row0 = blockIdx.x * GBM;

    // ---- stage A: fp32 -> f16, XOR-swizzled ----
    {
        const int row = t >> 2;                 // 0..127
        const int kq  = t & 3;
        int grow = row0 + row; if (grow >= M) grow = M - 1;
        const float* Ap = &A[(size_t)grow * IN_FEAT];
        #pragma unroll
        for (int i = 0; i < 8; ++i) {
            int k = kq * 8 + i * 32;
            float4 a0 = *(const float4*)(Ap + k);
            float4 a1 = *(const float4*)(Ap + k + 4);
            half8 h;
            h[0]=(_Float16)a0.x; h[1]=(_Float16)a0.y; h[2]=(_Float16)a0.z; h[3]=(_Float16)a0.w;
            h[4]=(_Float16)a1.x; h[5]=(_Float16)a1.y; h[6]=(_Float16)a1.z; h[7]=(_Float16)a1.w;
            int byte = row * 512 + k * 2;
            byte ^= (row & 7) << 4;
            *(half8*)((char*)sA + byte) = h;
        }
    }
    // ---- stage W^T: linear 64KB vector copy of the pre-swizzled image ----
    {
        const float4* src = (const float4*)wt;
        float4*       dst = (float4*)sW;
        #pragma unroll
        for (int i = 0; i < 8; ++i) dst[t + GT * i] = src[t + GT * i];
    }
    __syncthreads();

    // ---- compute: wave owns 16 rows x 128 cols; operands swapped ----
    const int wid  = t >> 6;
    const int lane = t & 63;
    const int rowBase = wid * 16;
    const int fr = lane & 15;
    const int fk = lane >> 4;

    f32x4 acc[8];
    #pragma unroll
    for (int nt = 0; nt < 8; ++nt) acc[nt] = (f32x4){0.f, 0.f, 0.f, 0.f};

    #pragma unroll
    for (int ks = 0; ks < 8; ++ks) {
        const int arow  = rowBase + fr;
        int abyte = arow * 512 + ks * 64 + fk * 16;
        abyte ^= (arow & 7) << 4;
        half8 af = *(const half8*)((const char*)sA + abyte);
        #pragma unroll
        for (int nt = 0; nt < 8; ++nt) {
            const int col = nt * 16 + fr;
            int bbyte = col * 512 + ks * 64 + fk * 16;
            bbyte ^= (col & 7) << 4;
            half8 bf = *(const half8*)((const char*)sW + bbyte);
            // swapped: D[m=Wcol][n=featrow] -> lane holds row (fr), cols fk*4+reg
            acc[nt] = __builtin_amdgcn_mfma_f32_16x16x32_f16(bf, af, acc[nt], 0, 0, 0);
        }
    }

    // ---- epilogue: lane = one row, 4 consecutive cols per nt ----
    const int grow = row0 + rowBase + fr;
    if (grow < M) {
        #pragma unroll
        for (int nt = 0; nt < 8; ++nt) {
            const int col0 = nt * 16 + fk * 4;
            float4 o = {acc[nt][0], acc[nt][1], acc[nt][2], acc[nt][3]};
            *(float4*)&C[(size_t)grow * OUT_FEAT + col0] = o;
            if (writeHalf) {
                half4 h = {(_Float16)o.x, (_Float16)o.y, (_Float16)o.z, (_Float16)o.w};
                *(half4*)&Ch[(size_t)grow * OUT_FEAT + col0] = h;
            }
        }
    }
}

// ---------------------------------------------------------------------------
// zero-fill x
// ---------------------------------------------------------------------------
__global__ void zero_kernel(float4* __restrict__ p, int n4)
{
    int i      = blockIdx.x * blockDim.x + threadIdx.x;
    int stride = gridDim.x * blockDim.x;
    for (; i < n4; i += stride) p[i] = float4{0.f, 0.f, 0.f, 0.f};
}

// ---------------------------------------------------------------------------
// SpMM over sorted COO (unchanged from R3/R5: ~138us).
// ---------------------------------------------------------------------------
#define EPB 512
#define EPW 128
#define PF  16

template<int USE_H>
__global__ __launch_bounds__(256) void spmm_kernel(
    const int*   __restrict__ erow, const int* __restrict__ ecol,
    const float* __restrict__ eval, const float* __restrict__ femb,
    const __half* __restrict__ fembh, float* __restrict__ x, int E)
{
    __shared__ int   s_row[EPB];
    __shared__ int   s_col[EPB];
    __shared__ float s_val[EPB];

    const int blockBase = blockIdx.x * EPB;

    #pragma unroll
    for (int i = 0; i < 2; ++i) {
        int li = threadIdx.x + i * 256;
        int e  = blockBase + li;
        if (e < E) {
            s_row[li] = __builtin_nontemporal_load(&erow[e]);
            s_col[li] = __builtin_nontemporal_load(&ecol[e]);
            s_val[li] = __builtin_nontemporal_load(&eval[e]);
        }
    }
    __syncthreads();

    const int wave = threadIdx.x >> 6;
    const int lane = threadIdx.x & 63;
    const int j    = lane * 2;

    const int w0 = wave * EPW;
    const int g0 = blockBase + w0;
    if (g0 >= E) return;
    const int n = min(EPW, E - g0);

    float2 acc = {0.f, 0.f};
    int cur = s_row[w0];

    if (n == EPW) {
        #pragma unroll 1
        for (int base = 0; base < EPW; base += PF) {
            __half2 h[PF];
            float2  f[PF];
            if constexpr (USE_H) {
                #pragma unroll
                for (int i = 0; i < PF; ++i) {
                    int c = s_col[w0 + base + i];
                    h[i] = *(const __half2*)&fembh[(size_t)c * OUT_FEAT + j];
                }
            } else {
                #pragma unroll
                for (int i = 0; i < PF; ++i) {
                    int c = s_col[w0 + base + i];
                    f[i] = *(const float2*)&femb[(size_t)c * OUT_FEAT + j];
                }
            }
            #pragma unroll
            for (int i = 0; i < PF; ++i) {
                int r = s_row[w0 + base + i];
                if (r != cur) {
                    atomicAdd(&x[(size_t)cur * OUT_FEAT + j],     acc.x);
                    atomicAdd(&x[(size_t)cur * OUT_FEAT + j + 1], acc.y);
                    acc.x = 0.f; acc.y = 0.f;
                    cur = r;
                }
                float v = s_val[w0 + base + i];
                float2 fv;
                if constexpr (USE_H) fv = __half22float2(h[i]); else fv = f[i];
                acc.x = fmaf(v, fv.x, acc.x);
                acc.y = fmaf(v, fv.y, acc.y);
            }
        }
    } else {
        for (int idx = 0; idx < n; ++idx) {
            int r = s_row[w0 + idx];
            if (r != cur) {
                atomicAdd(&x[(size_t)cur * OUT_FEAT + j],     acc.x);
                atomicAdd(&x[(size_t)cur * OUT_FEAT + j + 1], acc.y);
                acc.x = 0.f; acc.y = 0.f;
                cur = r;
            }
            int c = s_col[w0 + idx];
            float v = s_val[w0 + idx];
            float2 fv;
            if constexpr (USE_H) fv = __half22float2(*(const __half2*)&fembh[(size_t)c * OUT_FEAT + j]);
            else                 fv = *(const float2*)&femb[(size_t)c * OUT_FEAT + j];
            acc.x = fmaf(v, fv.x, acc.x);
            acc.y = fmaf(v, fv.y, acc.y);
        }
    }
    atomicAdd(&x[(size_t)cur * OUT_FEAT + j],     acc.x);
    atomicAdd(&x[(size_t)cur * OUT_FEAT + j + 1], acc.y);
}

// ---------------------------------------------------------------------------
extern "C" void kernel_launch(void* const* d_in, const int* in_sizes, int n_in,
                              void* d_out, int out_size, void* d_ws, size_t ws_size,
                              hipStream_t stream)
{
    const float* feat = (const float*)d_in[0];
    const int*   erow = (const int*)  d_in[1];
    const int*   ecol = (const int*)  d_in[2];
    const float* eval = (const float*)d_in[3];
    const float* W    = (const float*)d_in[4];

    const int M = in_sizes[0] / IN_FEAT;   // 100000
    const int E = in_sizes[1];             // 3200000

    float*  femb  = (float*)d_out;
    float*  x     = femb + (size_t)M * OUT_FEAT;
    char*   wt    = (char*)d_ws;                       // 64 KB W^T image
    __half* fembh = (__half*)((char*)d_ws + WT_BYTES); // fp16 femb copy

    const size_t needH = (size_t)WT_BYTES + (size_t)M * OUT_FEAT * sizeof(__half);
    const int useH = (ws_size >= needH) ? 1 : 0;

    wprep_kernel<<<64, 256, 0, stream>>>(W, wt);

    gemm_mfma_kernel<<<(M + GBM - 1) / GBM, GT, 0, stream>>>(feat, wt, femb, fembh, M, useH);

    zero_kernel<<<2048, 256, 0, stream>>>((float4*)x, (M * OUT_FEAT) / 4);

    int nblk = (E + EPB - 1) / EPB;
    if (useH) spmm_kernel<1><<<nblk, 256, 0, stream>>>(erow, ecol, eval, femb, fembh, x, E);
    else      spmm_kernel<0><<<nblk, 256, 0, stream>>>(erow, ecol, eval, femb, fembh, x, E);
}